// Round 1
// baseline (4410.527 us; speedup 1.0000x reference)
//
#include <hip/hip_runtime.h>
#include <math.h>

#define K_PATCHES 25
#define GRID_SIDE 20
#define G_PTS     400
#define LATENT    1024
#define BATCH     16
#define MT        16    // points per block in fused kernel

// ---------------------------------------------------------------------------
// Kernel 1: base[b][p][o] = b1[p][o] + sum_k x[b][k] * W1[p][k][o]   (o<1024)
// grid: 25 patches * 8 o-chunks (128 outputs each), block = 128 threads.
// Each thread holds 16 accumulators (all batches) so W1 is read exactly once.
// ---------------------------------------------------------------------------
__global__ __launch_bounds__(128)
void base_kernel(const float* __restrict__ x,
                 const float* __restrict__ W1,
                 const float* __restrict__ b1,
                 float* __restrict__ base) {
    __shared__ float xs[BATCH][LATENT];   // 64 KB
    const int p  = blockIdx.x >> 3;
    const int oc = blockIdx.x & 7;
    const int o  = oc * 128 + threadIdx.x;

    // stage all of x (16x1024 fp32) into LDS, vectorized
    for (int idx = threadIdx.x; idx < BATCH * LATENT / 4; idx += 128)
        ((float4*)xs)[idx] = ((const float4*)x)[idx];
    __syncthreads();

    float acc[BATCH];
#pragma unroll
    for (int b = 0; b < BATCH; ++b) acc[b] = 0.0f;

    const float* Wp = W1 + (size_t)p * 1026 * 1024 + o;
    for (int k = 0; k < LATENT; k += 4) {
        const float w0 = Wp[(size_t)(k + 0) * 1024];
        const float w1 = Wp[(size_t)(k + 1) * 1024];
        const float w2 = Wp[(size_t)(k + 2) * 1024];
        const float w3 = Wp[(size_t)(k + 3) * 1024];
#pragma unroll
        for (int b = 0; b < BATCH; ++b) {
            const float4 xv = *(const float4*)&xs[b][k];
            acc[b] = fmaf(xv.w, w3, fmaf(xv.z, w2, fmaf(xv.y, w1, fmaf(xv.x, w0, acc[b]))));
        }
    }

    const float bias = b1[p * 1024 + o];
    for (int b = 0; b < BATCH; ++b)
        base[(size_t)(b * K_PATCHES + p) * 1024 + o] = acc[b] + bias;
}

// ---------------------------------------------------------------------------
// Kernel 2: fused layers 2..5 for a tile of MT=16 points of one (b, p).
// h1[m][k] = relu(base[k] + u_m*W1[p][1024][k] + v_m*W1[p][1025][k]) computed
// on the fly (no 64KB h1 buffer). Thread map: wave (tid>>6) owns 4 m-rows,
// lane (tid&63) owns a contiguous float4/float2 slice of outputs.
// LDS: 12KB (base/wu/wv) + 32KB h2 + 16KB h3 + 8KB h4 = 68KB -> 2 blocks/CU.
// grid order: blk = p*400 + b*25 + gt  (patch slowest -> W2[p] stays in L2).
// ---------------------------------------------------------------------------
__global__ __launch_bounds__(256, 2)
void mlp_kernel(const float* __restrict__ base,
                const float* __restrict__ W1,
                const float* __restrict__ W2, const float* __restrict__ b2,
                const float* __restrict__ W3, const float* __restrict__ b3,
                const float* __restrict__ W4, const float* __restrict__ b4,
                const float* __restrict__ W5, const float* __restrict__ b5,
                float* __restrict__ out) {
    __shared__ float sbase[1024];
    __shared__ float swu[1024];
    __shared__ float swv[1024];
    __shared__ float h2[MT][512];
    __shared__ float h3[MT][256];
    __shared__ float h4[MT][128];

    const int blk = blockIdx.x;
    const int p   = blk / (BATCH * 25);
    const int rem = blk % (BATCH * 25);
    const int b   = rem / 25;
    const int gt  = rem % 25;
    const int tid  = threadIdx.x;
    const int wave = tid >> 6;   // 0..3
    const int lane = tid & 63;

    // stage base row (with b1 folded in) + uv weight rows
    {
        const float* bp  = base + (size_t)(b * K_PATCHES + p) * 1024;
        const float* wup = W1 + (size_t)p * 1026 * 1024 + (size_t)1024 * 1024;
        const float* wvp = wup + 1024;
        ((float4*)sbase)[tid] = ((const float4*)bp)[tid];   // 256 float4 == 1024 floats
        ((float4*)swu)[tid]   = ((const float4*)wup)[tid];
        ((float4*)swv)[tid]   = ((const float4*)wvp)[tid];
    }
    __syncthreads();

    // uv for this thread's 4 points (m = wave*4+i)
    float u[4], v[4];
#pragma unroll
    for (int i = 0; i < 4; ++i) {
        const int g = gt * MT + wave * 4 + i;
        u[i] = (float)(g % GRID_SIDE) * (1.0f / 19.0f);
        v[i] = (float)(g / GRID_SIDE) * (1.0f / 19.0f);
    }

    // ---- Layer 2: (16 x 512), K=1024, outputs o = lane*8 + n ----
    {
        float acc[4][8];
        const float* b2p = b2 + p * 512;
#pragma unroll
        for (int n = 0; n < 8; ++n) {
            const float bias = b2p[lane * 8 + n];
#pragma unroll
            for (int i = 0; i < 4; ++i) acc[i][n] = bias;
        }
        const float* W2p = W2 + (size_t)p * 1024 * 512;
#pragma unroll 2
        for (int k = 0; k < 1024; ++k) {
            const float s = sbase[k], wuk = swu[k], wvk = swv[k];
            float a[4];
#pragma unroll
            for (int i = 0; i < 4; ++i)
                a[i] = fmaxf(fmaf(v[i], wvk, fmaf(u[i], wuk, s)), 0.0f);
            const float4 w0 = *(const float4*)&W2p[(size_t)k * 512 + lane * 8];
            const float4 w1 = *(const float4*)&W2p[(size_t)k * 512 + lane * 8 + 4];
#pragma unroll
            for (int i = 0; i < 4; ++i) {
                acc[i][0] = fmaf(a[i], w0.x, acc[i][0]);
                acc[i][1] = fmaf(a[i], w0.y, acc[i][1]);
                acc[i][2] = fmaf(a[i], w0.z, acc[i][2]);
                acc[i][3] = fmaf(a[i], w0.w, acc[i][3]);
                acc[i][4] = fmaf(a[i], w1.x, acc[i][4]);
                acc[i][5] = fmaf(a[i], w1.y, acc[i][5]);
                acc[i][6] = fmaf(a[i], w1.z, acc[i][6]);
                acc[i][7] = fmaf(a[i], w1.w, acc[i][7]);
            }
        }
#pragma unroll
        for (int i = 0; i < 4; ++i) {
            const int m = wave * 4 + i;
            float4 r0, r1;
            r0.x = fmaxf(acc[i][0], 0.0f); r0.y = fmaxf(acc[i][1], 0.0f);
            r0.z = fmaxf(acc[i][2], 0.0f); r0.w = fmaxf(acc[i][3], 0.0f);
            r1.x = fmaxf(acc[i][4], 0.0f); r1.y = fmaxf(acc[i][5], 0.0f);
            r1.z = fmaxf(acc[i][6], 0.0f); r1.w = fmaxf(acc[i][7], 0.0f);
            *(float4*)&h2[m][lane * 8]     = r0;
            *(float4*)&h2[m][lane * 8 + 4] = r1;
        }
    }
    __syncthreads();

    // ---- Layer 3: (16 x 256), K=512, outputs o = lane*4 + n ----
    {
        float acc[4][4];
        const float* b3p = b3 + p * 256;
#pragma unroll
        for (int n = 0; n < 4; ++n) {
            const float bias = b3p[lane * 4 + n];
#pragma unroll
            for (int i = 0; i < 4; ++i) acc[i][n] = bias;
        }
        const float* W3p = W3 + (size_t)p * 512 * 256;
#pragma unroll 4
        for (int k = 0; k < 512; ++k) {
            const float4 w = *(const float4*)&W3p[(size_t)k * 256 + lane * 4];
#pragma unroll
            for (int i = 0; i < 4; ++i) {
                const float a = h2[wave * 4 + i][k];
                acc[i][0] = fmaf(a, w.x, acc[i][0]);
                acc[i][1] = fmaf(a, w.y, acc[i][1]);
                acc[i][2] = fmaf(a, w.z, acc[i][2]);
                acc[i][3] = fmaf(a, w.w, acc[i][3]);
            }
        }
#pragma unroll
        for (int i = 0; i < 4; ++i) {
            const int m = wave * 4 + i;
            float4 r;
            r.x = fmaxf(acc[i][0], 0.0f); r.y = fmaxf(acc[i][1], 0.0f);
            r.z = fmaxf(acc[i][2], 0.0f); r.w = fmaxf(acc[i][3], 0.0f);
            *(float4*)&h3[m][lane * 4] = r;
        }
    }
    __syncthreads();

    // ---- Layer 4: (16 x 128), K=256, outputs o = lane*2 + n ----
    {
        float acc[4][2];
        const float* b4p = b4 + p * 128;
        {
            const float bias0 = b4p[lane * 2];
            const float bias1 = b4p[lane * 2 + 1];
#pragma unroll
            for (int i = 0; i < 4; ++i) { acc[i][0] = bias0; acc[i][1] = bias1; }
        }
        const float* W4p = W4 + (size_t)p * 256 * 128;
#pragma unroll 4
        for (int k = 0; k < 256; ++k) {
            const float2 w = *(const float2*)&W4p[(size_t)k * 128 + lane * 2];
#pragma unroll
            for (int i = 0; i < 4; ++i) {
                const float a = h3[wave * 4 + i][k];
                acc[i][0] = fmaf(a, w.x, acc[i][0]);
                acc[i][1] = fmaf(a, w.y, acc[i][1]);
            }
        }
#pragma unroll
        for (int i = 0; i < 4; ++i) {
            const int m = wave * 4 + i;
            float2 r;
            r.x = fmaxf(acc[i][0], 0.0f);
            r.y = fmaxf(acc[i][1], 0.0f);
            *(float2*)&h4[m][lane * 2] = r;
        }
    }
    __syncthreads();

    // ---- Layer 5: (16 x 3), K=128, tanh, store ----
    if (tid < MT * 3) {
        const int m = tid / 3;
        const int c = tid % 3;
        const float* W5p = W5 + p * 128 * 3;
        float acc = b5[p * 3 + c];
#pragma unroll 4
        for (int k = 0; k < 128; ++k)
            acc = fmaf(h4[m][k], W5p[k * 3 + c], acc);
        const int g = gt * MT + m;
        out[((size_t)(b * K_PATCHES + p) * G_PTS + g) * 3 + c] = tanhf(acc);
    }
}

extern "C" void kernel_launch(void* const* d_in, const int* in_sizes, int n_in,
                              void* d_out, int out_size, void* d_ws, size_t ws_size,
                              hipStream_t stream) {
    const float* x  = (const float*)d_in[0];
    const float* W1 = (const float*)d_in[1];
    const float* b1 = (const float*)d_in[2];
    const float* W2 = (const float*)d_in[3];
    const float* b2 = (const float*)d_in[4];
    const float* W3 = (const float*)d_in[5];
    const float* b3 = (const float*)d_in[6];
    const float* W4 = (const float*)d_in[7];
    const float* b4 = (const float*)d_in[8];
    const float* W5 = (const float*)d_in[9];
    const float* b5 = (const float*)d_in[10];
    float* out  = (float*)d_out;
    float* base = (float*)d_ws;   // BATCH*K_PATCHES*1024 fp32 = 1.6 MB

    // Kernel 1: latent @ W1_lat precompute (exploits latent broadcast over G)
    base_kernel<<<K_PATCHES * 8, 128, 0, stream>>>(x, W1, b1, base);

    // Kernel 2: fused per-point MLP, patch-major grid for W-reuse in L2
    mlp_kernel<<<K_PATCHES * BATCH * (G_PTS / MT), 256, 0, stream>>>(
        base, W1, W2, b2, W3, b3, W4, b4, W5, b5, out);
}

// Round 2
// 986.804 us; speedup vs baseline: 4.4695x; 4.4695x over previous
//
#include <hip/hip_runtime.h>
#include <math.h>

#define K_PATCHES 25
#define GRID_SIDE 20
#define G_PTS     400
#define LATENT    1024
#define BATCH     16

typedef _Float16 f16x8 __attribute__((ext_vector_type(8)));
typedef float    f32x4 __attribute__((ext_vector_type(4)));

// ws layout (bytes)
#define BASE_OFF 0                      // 16*25*1024 f32 = 1,638,400
#define WT2_OFF  1638400                // 25*512*1024 f16 = 26,214,400
#define WT3_OFF  27852800               // 25*256*512 f16  =  6,553,600
#define WT4_OFF  34406400               // 25*128*256 f16  =  1,638,400
// total 36,044,800 B

// ---------------------------------------------------------------------------
// Kernel 1: base[b][p][o] = b1[p][o] + sum_k x[b][k]*W1[p][k][o]  (o<1024)
// (latent is broadcast over all 400 grid points -> compute once per (b,p))
// ---------------------------------------------------------------------------
__global__ __launch_bounds__(128)
void base_kernel(const float* __restrict__ x,
                 const float* __restrict__ W1,
                 const float* __restrict__ b1,
                 float* __restrict__ base) {
    __shared__ float xs[BATCH][LATENT];   // 64 KB
    const int p  = blockIdx.x >> 3;
    const int oc = blockIdx.x & 7;
    const int o  = oc * 128 + threadIdx.x;

    for (int idx = threadIdx.x; idx < BATCH * LATENT / 4; idx += 128)
        ((float4*)xs)[idx] = ((const float4*)x)[idx];
    __syncthreads();

    float acc[BATCH];
#pragma unroll
    for (int b = 0; b < BATCH; ++b) acc[b] = 0.0f;

    const float* Wp = W1 + (size_t)p * 1026 * 1024 + o;
    for (int k = 0; k < LATENT; k += 4) {
        const float w0 = Wp[(size_t)(k + 0) * 1024];
        const float w1 = Wp[(size_t)(k + 1) * 1024];
        const float w2 = Wp[(size_t)(k + 2) * 1024];
        const float w3 = Wp[(size_t)(k + 3) * 1024];
#pragma unroll
        for (int b = 0; b < BATCH; ++b) {
            const float4 xv = *(const float4*)&xs[b][k];
            acc[b] = fmaf(xv.w, w3, fmaf(xv.z, w2, fmaf(xv.y, w1, fmaf(xv.x, w0, acc[b]))));
        }
    }

    const float bias = b1[p * 1024 + o];
    for (int b = 0; b < BATCH; ++b)
        base[(size_t)(b * K_PATCHES + p) * 1024 + o] = acc[b] + bias;
}

// ---------------------------------------------------------------------------
// Transpose + fp16 convert: W[p][K][N] f32 -> Wt[p][N][K] f16.
// 64x64 tiles via LDS (padded stride 65 -> conflict-free column reads).
// ---------------------------------------------------------------------------
__global__ __launch_bounds__(256)
void conv_tr_kernel(const float* __restrict__ W, _Float16* __restrict__ Wt,
                    int K, int N) {
    __shared__ float tile[64][65];
    const int tpp = (K / 64) * (N / 64);
    const int p   = blockIdx.x / tpp;
    const int rem = blockIdx.x % tpp;
    const int kt  = rem / (N / 64);
    const int nt  = rem % (N / 64);
    const int tr  = threadIdx.x >> 6;   // 0..3
    const int tc  = threadIdx.x & 63;

    const float* Wp = W + ((size_t)p * K + kt * 64) * N + nt * 64;
#pragma unroll
    for (int i = 0; i < 64; i += 4)
        tile[i + tr][tc] = Wp[(size_t)(i + tr) * N + tc];
    __syncthreads();

    _Float16* Wtp = Wt + ((size_t)p * N + nt * 64) * K + kt * 64;
#pragma unroll
    for (int i = 0; i < 64; i += 4)
        Wtp[(size_t)(i + tr) * K + tc] = (_Float16)tile[tc][i + tr];
}

// ---------------------------------------------------------------------------
// Fused MFMA kernel: layers 2..5 for 64 rows of one patch's 6400-row GEMM.
// 8 waves (2M x 4N). h1 built on the fly per 64-K chunk into swizzled LDS.
// All LDS activation tiles XOR-swizzled (byte ^= (row&7)<<4) so ds_read_b128
// A-fragments are 2-way (free) instead of 16-way conflicts.
// ---------------------------------------------------------------------------
__global__ __launch_bounds__(512, 1)
void fused_mfma(const float* __restrict__ base,
                const float* __restrict__ W1,
                const _Float16* __restrict__ Wt2, const float* __restrict__ b2,
                const _Float16* __restrict__ Wt3, const float* __restrict__ b3,
                const _Float16* __restrict__ Wt4, const float* __restrict__ b4,
                const float* __restrict__ W5, const float* __restrict__ b5,
                float* __restrict__ out) {
    __shared__ __align__(16) float sb[2][1024];           // 8 KB  base rows
    __shared__ __align__(16) float swu[1024];             // 4 KB
    __shared__ __align__(16) float swv[1024];             // 4 KB
    __shared__ __align__(16) unsigned char h1s[64 * 64 * 2];    // 8 KB
    __shared__ __align__(16) unsigned char h2s[64 * 512 * 2];   // 64 KB
    __shared__ __align__(16) unsigned char h3s[64 * 256 * 2];   // 32 KB
    __shared__ __align__(16) unsigned char h4s[64 * 128 * 2];   // 16 KB

    // ---- bijective XCD swizzle: 2500 blocks -> 8 XCDs, same-patch adjacency
    const int bid = blockIdx.x;
    const int xcd = bid & 7;
    const int ii  = bid >> 3;
    // 2500 = 8*312 + 4 : xcd 0..3 own 313 blocks, 4..7 own 312
    const int ord = (xcd < 4) ? xcd * 313 + ii : 4 * 313 + (xcd - 4) * 312 + ii;
    const int p     = ord / 100;
    const int rbase = (ord % 100) * 64;   // row tile within patch (6400 rows)

    const int t    = threadIdx.x;
    const int lane = t & 63;
    const int w    = t >> 6;
    const int wm   = w >> 2;      // 0..1  (32-row half)
    const int wn   = w & 3;       // 0..3  (N slice)
    const int l16  = lane & 15;
    const int lq   = lane >> 4;   // 0..3

    // ---- stage base rows (this tile spans at most 2 batch values) + uv rows
    const int b0 = rbase / 400;
    const int b1 = (rbase + 63) / 400;
    {
        const float* base0 = base + (size_t)(b0 * K_PATCHES + p) * 1024;
        const float* base1 = base + (size_t)(b1 * K_PATCHES + p) * 1024;
        const float* wup   = W1 + (size_t)p * 1026 * 1024 + (size_t)1024 * 1024;
        if (t < 256) ((float4*)sb[0])[t] = ((const float4*)base0)[t];
        else         ((float4*)sb[1])[t - 256] = ((const float4*)base1)[t - 256];
        if (t < 256) ((float4*)swu)[t] = ((const float4*)wup)[t];
        else         ((float4*)swv)[t - 256] = ((const float4*)(wup + 1024))[t - 256];
    }
    __syncthreads();

    // ---- per-thread h1-producer constants (thread t owns row hm, k-octet hj)
    const int hm = t >> 3;             // 0..63
    const int hj = (t & 7) * 8;        // 0,8,..,56
    const int rr = rbase + hm;
    const float* sbm = (rr < (b0 + 1) * 400) ? sb[0] : sb[1];
    const int g  = rr % 400;
    const float um = (float)(g % GRID_SIDE) * (1.0f / 19.0f);
    const float vm = (float)(g / GRID_SIDE) * (1.0f / 19.0f);
    const unsigned hwoff = (unsigned)((hm * 128 + hj * 2) ^ ((hm & 7) << 4));

    // =======================  Layer 2: 64x512, K=1024  ======================
    f32x4 acc2[2][8];
    {
        const float* b2p = b2 + p * 512;
#pragma unroll
        for (int nf = 0; nf < 8; ++nf) {
            const float bias = b2p[wn * 128 + nf * 16 + l16];
            f32x4 bv = {bias, bias, bias, bias};
            acc2[0][nf] = bv;
            acc2[1][nf] = bv;
        }
    }
    const _Float16* Wt2p = Wt2 + (size_t)p * 512 * 1024;

    for (int kc = 0; kc < 1024; kc += 64) {
        // produce h1 chunk [64 rows][64 k] fp16, swizzled
        {
            const float4 bv0 = *(const float4*)&sbm[kc + hj];
            const float4 bv1 = *(const float4*)&sbm[kc + hj + 4];
            const float4 u0  = *(const float4*)&swu[kc + hj];
            const float4 u1  = *(const float4*)&swu[kc + hj + 4];
            const float4 v0  = *(const float4*)&swv[kc + hj];
            const float4 v1  = *(const float4*)&swv[kc + hj + 4];
            f16x8 hv;
            hv[0] = (_Float16)fmaxf(fmaf(vm, v0.x, fmaf(um, u0.x, bv0.x)), 0.0f);
            hv[1] = (_Float16)fmaxf(fmaf(vm, v0.y, fmaf(um, u0.y, bv0.y)), 0.0f);
            hv[2] = (_Float16)fmaxf(fmaf(vm, v0.z, fmaf(um, u0.z, bv0.z)), 0.0f);
            hv[3] = (_Float16)fmaxf(fmaf(vm, v0.w, fmaf(um, u0.w, bv0.w)), 0.0f);
            hv[4] = (_Float16)fmaxf(fmaf(vm, v1.x, fmaf(um, u1.x, bv1.x)), 0.0f);
            hv[5] = (_Float16)fmaxf(fmaf(vm, v1.y, fmaf(um, u1.y, bv1.y)), 0.0f);
            hv[6] = (_Float16)fmaxf(fmaf(vm, v1.z, fmaf(um, u1.z, bv1.z)), 0.0f);
            hv[7] = (_Float16)fmaxf(fmaf(vm, v1.w, fmaf(um, u1.w, bv1.w)), 0.0f);
            *(f16x8*)(h1s + hwoff) = hv;
        }
        __syncthreads();

#pragma unroll
        for (int ks = 0; ks < 64; ks += 32) {
            const int kb = (ks + lq * 8) * 2;
            const int r0 = wm * 32 + l16;
            const int r1 = r0 + 16;
            const f16x8 a0 = *(const f16x8*)(h1s + ((r0 * 128 + kb) ^ ((r0 & 7) << 4)));
            const f16x8 a1 = *(const f16x8*)(h1s + ((r1 * 128 + kb) ^ ((r1 & 7) << 4)));
#pragma unroll
            for (int nf = 0; nf < 8; ++nf) {
                const int n = wn * 128 + nf * 16 + l16;
                const f16x8 bf = *(const f16x8*)&Wt2p[(size_t)n * 1024 + kc + ks + lq * 8];
                acc2[0][nf] = __builtin_amdgcn_mfma_f32_16x16x32_f16(a0, bf, acc2[0][nf], 0, 0, 0);
                acc2[1][nf] = __builtin_amdgcn_mfma_f32_16x16x32_f16(a1, bf, acc2[1][nf], 0, 0, 0);
            }
        }
        __syncthreads();
    }
    // store h2 = relu(acc2) as fp16, swizzled
#pragma unroll
    for (int msi = 0; msi < 2; ++msi)
#pragma unroll
        for (int nf = 0; nf < 8; ++nf)
#pragma unroll
            for (int r = 0; r < 4; ++r) {
                const int row = wm * 32 + msi * 16 + lq * 4 + r;
                const int col = wn * 128 + nf * 16 + l16;
                const float v = fmaxf(acc2[msi][nf][r], 0.0f);
                *(_Float16*)(h2s + ((row * 1024 + col * 2) ^ ((row & 7) << 4))) = (_Float16)v;
            }
    __syncthreads();

    // =======================  Layer 3: 64x256, K=512  =======================
    f32x4 acc3[2][4];
    {
        const float* b3p = b3 + p * 256;
#pragma unroll
        for (int nf = 0; nf < 4; ++nf) {
            const float bias = b3p[wn * 64 + nf * 16 + l16];
            f32x4 bv = {bias, bias, bias, bias};
            acc3[0][nf] = bv;
            acc3[1][nf] = bv;
        }
    }
    const _Float16* Wt3p = Wt3 + (size_t)p * 256 * 512;
#pragma unroll 2
    for (int ks = 0; ks < 512; ks += 32) {
        const int kb = (ks + lq * 8) * 2;
        const int r0 = wm * 32 + l16;
        const int r1 = r0 + 16;
        const f16x8 a0 = *(const f16x8*)(h2s + ((r0 * 1024 + kb) ^ ((r0 & 7) << 4)));
        const f16x8 a1 = *(const f16x8*)(h2s + ((r1 * 1024 + kb) ^ ((r1 & 7) << 4)));
#pragma unroll
        for (int nf = 0; nf < 4; ++nf) {
            const int n = wn * 64 + nf * 16 + l16;
            const f16x8 bf = *(const f16x8*)&Wt3p[(size_t)n * 512 + ks + lq * 8];
            acc3[0][nf] = __builtin_amdgcn_mfma_f32_16x16x32_f16(a0, bf, acc3[0][nf], 0, 0, 0);
            acc3[1][nf] = __builtin_amdgcn_mfma_f32_16x16x32_f16(a1, bf, acc3[1][nf], 0, 0, 0);
        }
    }
#pragma unroll
    for (int msi = 0; msi < 2; ++msi)
#pragma unroll
        for (int nf = 0; nf < 4; ++nf)
#pragma unroll
            for (int r = 0; r < 4; ++r) {
                const int row = wm * 32 + msi * 16 + lq * 4 + r;
                const int col = wn * 64 + nf * 16 + l16;
                const float v = fmaxf(acc3[msi][nf][r], 0.0f);
                *(_Float16*)(h3s + ((row * 512 + col * 2) ^ ((row & 7) << 4))) = (_Float16)v;
            }
    __syncthreads();

    // =======================  Layer 4: 64x128, K=256  =======================
    f32x4 acc4[2][2];
    {
        const float* b4p = b4 + p * 128;
#pragma unroll
        for (int nf = 0; nf < 2; ++nf) {
            const float bias = b4p[wn * 32 + nf * 16 + l16];
            f32x4 bv = {bias, bias, bias, bias};
            acc4[0][nf] = bv;
            acc4[1][nf] = bv;
        }
    }
    const _Float16* Wt4p = Wt4 + (size_t)p * 128 * 256;
#pragma unroll
    for (int ks = 0; ks < 256; ks += 32) {
        const int kb = (ks + lq * 8) * 2;
        const int r0 = wm * 32 + l16;
        const int r1 = r0 + 16;
        const f16x8 a0 = *(const f16x8*)(h3s + ((r0 * 512 + kb) ^ ((r0 & 7) << 4)));
        const f16x8 a1 = *(const f16x8*)(h3s + ((r1 * 512 + kb) ^ ((r1 & 7) << 4)));
#pragma unroll
        for (int nf = 0; nf < 2; ++nf) {
            const int n = wn * 32 + nf * 16 + l16;
            const f16x8 bf = *(const f16x8*)&Wt4p[(size_t)n * 256 + ks + lq * 8];
            acc4[0][nf] = __builtin_amdgcn_mfma_f32_16x16x32_f16(a0, bf, acc4[0][nf], 0, 0, 0);
            acc4[1][nf] = __builtin_amdgcn_mfma_f32_16x16x32_f16(a1, bf, acc4[1][nf], 0, 0, 0);
        }
    }
#pragma unroll
    for (int msi = 0; msi < 2; ++msi)
#pragma unroll
        for (int nf = 0; nf < 2; ++nf)
#pragma unroll
            for (int r = 0; r < 4; ++r) {
                const int row = wm * 32 + msi * 16 + lq * 4 + r;
                const int col = wn * 32 + nf * 16 + l16;
                const float v = fmaxf(acc4[msi][nf][r], 0.0f);
                *(_Float16*)(h4s + ((row * 256 + col * 2) ^ ((row & 7) << 4))) = (_Float16)v;
            }
    __syncthreads();

    // =======================  Layer 5: 64x3, K=128, tanh  ===================
    if (t < 192) {
        const int m = t / 3;
        const int c = t % 3;
        const float* W5p = W5 + p * 128 * 3;
        float acc = b5[p * 3 + c];
#pragma unroll 4
        for (int k = 0; k < 128; ++k) {
            const _Float16 hv = *(const _Float16*)(h4s + ((m * 256 + k * 2) ^ ((m & 7) << 4)));
            acc = fmaf((float)hv, W5p[k * 3 + c], acc);
        }
        const int r  = rbase + m;
        const int bb = r / 400;
        const int gg = r % 400;
        out[((size_t)(bb * K_PATCHES + p) * G_PTS + gg) * 3 + c] = tanhf(acc);
    }
}

extern "C" void kernel_launch(void* const* d_in, const int* in_sizes, int n_in,
                              void* d_out, int out_size, void* d_ws, size_t ws_size,
                              hipStream_t stream) {
    const float* x  = (const float*)d_in[0];
    const float* W1 = (const float*)d_in[1];
    const float* b1 = (const float*)d_in[2];
    const float* W2 = (const float*)d_in[3];
    const float* b2 = (const float*)d_in[4];
    const float* W3 = (const float*)d_in[5];
    const float* b3 = (const float*)d_in[6];
    const float* W4 = (const float*)d_in[7];
    const float* b4 = (const float*)d_in[8];
    const float* W5 = (const float*)d_in[9];
    const float* b5 = (const float*)d_in[10];
    float* out = (float*)d_out;

    float*     base = (float*)((char*)d_ws + BASE_OFF);
    _Float16*  Wt2  = (_Float16*)((char*)d_ws + WT2_OFF);
    _Float16*  Wt3  = (_Float16*)((char*)d_ws + WT3_OFF);
    _Float16*  Wt4  = (_Float16*)((char*)d_ws + WT4_OFF);

    // 1) latent @ W1 precompute (bias folded)
    base_kernel<<<K_PATCHES * 8, 128, 0, stream>>>(x, W1, b1, base);

    // 2) transpose+convert weights to fp16 [p][N][K]
    conv_tr_kernel<<<K_PATCHES * (1024 / 64) * (512 / 64), 256, 0, stream>>>(W2, Wt2, 1024, 512);
    conv_tr_kernel<<<K_PATCHES * (512 / 64) * (256 / 64),  256, 0, stream>>>(W3, Wt3, 512, 256);
    conv_tr_kernel<<<K_PATCHES * (256 / 64) * (128 / 64),  256, 0, stream>>>(W4, Wt4, 256, 128);

    // 3) fused MFMA layers 2..5
    fused_mfma<<<K_PATCHES * 100, 512, 0, stream>>>(
        base, W1, Wt2, b2, Wt3, b3, Wt4, b4, W5, b5, out);
}

// Round 3
// 956.377 us; speedup vs baseline: 4.6117x; 1.0318x over previous
//
#include <hip/hip_runtime.h>
#include <math.h>

#define K_PATCHES 25
#define GRID_SIDE 20
#define G_PTS     400
#define LATENT    1024
#define BATCH     16

typedef _Float16 f16x8 __attribute__((ext_vector_type(8)));
typedef float    f32x4 __attribute__((ext_vector_type(4)));

// ws layout (bytes)
#define BASE_OFF 0                      // 16*25*1024 f32 = 1,638,400
#define WT2_OFF  1638400                // 25*512*1024 f16 = 26,214,400
#define WT3_OFF  27852800               // 25*256*512 f16  =  6,553,600
#define WT4_OFF  34406400               // 25*128*256 f16  =  1,638,400

// ---------------------------------------------------------------------------
// Kernel 1: base[b][p][o] = b1[p][o] + sum_k x[b][k]*W1[p][k][o]  (o<1024)
// ---------------------------------------------------------------------------
__global__ __launch_bounds__(128)
void base_kernel(const float* __restrict__ x,
                 const float* __restrict__ W1,
                 const float* __restrict__ b1,
                 float* __restrict__ base) {
    __shared__ float xs[BATCH][LATENT];   // 64 KB
    const int p  = blockIdx.x >> 3;
    const int oc = blockIdx.x & 7;
    const int o  = oc * 128 + threadIdx.x;

    for (int idx = threadIdx.x; idx < BATCH * LATENT / 4; idx += 128)
        ((float4*)xs)[idx] = ((const float4*)x)[idx];
    __syncthreads();

    float acc[BATCH];
#pragma unroll
    for (int b = 0; b < BATCH; ++b) acc[b] = 0.0f;

    const float* Wp = W1 + (size_t)p * 1026 * 1024 + o;
    for (int k = 0; k < LATENT; k += 4) {
        const float w0 = Wp[(size_t)(k + 0) * 1024];
        const float w1 = Wp[(size_t)(k + 1) * 1024];
        const float w2 = Wp[(size_t)(k + 2) * 1024];
        const float w3 = Wp[(size_t)(k + 3) * 1024];
#pragma unroll
        for (int b = 0; b < BATCH; ++b) {
            const float4 xv = *(const float4*)&xs[b][k];
            acc[b] = fmaf(xv.w, w3, fmaf(xv.z, w2, fmaf(xv.y, w1, fmaf(xv.x, w0, acc[b]))));
        }
    }

    const float bias = b1[p * 1024 + o];
    for (int b = 0; b < BATCH; ++b)
        base[(size_t)(b * K_PATCHES + p) * 1024 + o] = acc[b] + bias;
}

// ---------------------------------------------------------------------------
// Transpose + fp16 convert: W[p][K][N] f32 -> Wt[p][N][K] f16.
// ---------------------------------------------------------------------------
__global__ __launch_bounds__(256)
void conv_tr_kernel(const float* __restrict__ W, _Float16* __restrict__ Wt,
                    int K, int N) {
    __shared__ float tile[64][65];
    const int tpp = (K / 64) * (N / 64);
    const int p   = blockIdx.x / tpp;
    const int rem = blockIdx.x % tpp;
    const int kt  = rem / (N / 64);
    const int nt  = rem % (N / 64);
    const int tr  = threadIdx.x >> 6;
    const int tc  = threadIdx.x & 63;

    const float* Wp = W + ((size_t)p * K + kt * 64) * N + nt * 64;
#pragma unroll
    for (int i = 0; i < 64; i += 4)
        tile[i + tr][tc] = Wp[(size_t)(i + tr) * N + tc];
    __syncthreads();

    _Float16* Wtp = Wt + ((size_t)p * N + nt * 64) * K + kt * 64;
#pragma unroll
    for (int i = 0; i < 64; i += 4)
        Wtp[(size_t)(i + tr) * K + tc] = (_Float16)tile[tc][i + tr];
}

// ---------------------------------------------------------------------------
// Fused MFMA kernel, pipelined:
//  - h1 double-buffered (1 barrier per 64-K chunk)
//  - next chunk's B fragments register-prefetched a full chunk ahead
//  - h1 production for chunk k+1 overlaps MFMA-wait of chunk k
//  - s_setprio(1) around MFMA cluster
// ---------------------------------------------------------------------------
__global__ __launch_bounds__(512, 2)
void fused_mfma(const float* __restrict__ base,
                const float* __restrict__ W1,
                const _Float16* __restrict__ Wt2, const float* __restrict__ b2,
                const _Float16* __restrict__ Wt3, const float* __restrict__ b3,
                const _Float16* __restrict__ Wt4, const float* __restrict__ b4,
                const float* __restrict__ W5, const float* __restrict__ b5,
                float* __restrict__ out) {
    __shared__ __align__(16) float sb[2][1024];                  // 8 KB
    __shared__ __align__(16) float swu[1024];                    // 4 KB
    __shared__ __align__(16) float swv[1024];                    // 4 KB
    __shared__ __align__(16) unsigned char h1s[2][64 * 64 * 2];  // 16 KB (dbuf)
    __shared__ __align__(16) unsigned char h2s[64 * 512 * 2];    // 64 KB
    __shared__ __align__(16) unsigned char h3s[64 * 256 * 2];    // 32 KB
    __shared__ __align__(16) unsigned char h4s[64 * 128 * 2];    // 16 KB
    // total 144 KB -> 1 block/CU

    const int bid = blockIdx.x;
    const int xcd = bid & 7;
    const int ii  = bid >> 3;
    const int ord = (xcd < 4) ? xcd * 313 + ii : 4 * 313 + (xcd - 4) * 312 + ii;
    const int p     = ord / 100;
    const int rbase = (ord % 100) * 64;

    const int t    = threadIdx.x;
    const int lane = t & 63;
    const int w    = t >> 6;
    const int wm   = w >> 2;      // 0..1
    const int wn   = w & 3;       // 0..3
    const int l16  = lane & 15;
    const int lq   = lane >> 4;   // 0..3

    const int b0 = rbase / 400;
    const int b1 = (rbase + 63) / 400;
    {
        const float* base0 = base + (size_t)(b0 * K_PATCHES + p) * 1024;
        const float* base1 = base + (size_t)(b1 * K_PATCHES + p) * 1024;
        const float* wup   = W1 + (size_t)p * 1026 * 1024 + (size_t)1024 * 1024;
        if (t < 256) ((float4*)sb[0])[t] = ((const float4*)base0)[t];
        else         ((float4*)sb[1])[t - 256] = ((const float4*)base1)[t - 256];
        if (t < 256) ((float4*)swu)[t] = ((const float4*)wup)[t];
        else         ((float4*)swv)[t - 256] = ((const float4*)(wup + 1024))[t - 256];
    }
    __syncthreads();

    // h1 producer constants: thread t owns row hm, k-octet hj
    const int hm = t >> 3;
    const int hj = (t & 7) * 8;
    const int rr = rbase + hm;
    const float* sbm = (rr < (b0 + 1) * 400) ? sb[0] : sb[1];
    const int g  = rr % 400;
    const float um = (float)(g % GRID_SIDE) * (1.0f / 19.0f);
    const float vm = (float)(g / GRID_SIDE) * (1.0f / 19.0f);
    const unsigned hwoff = (unsigned)((hm * 128 + hj * 2) ^ ((hm & 7) << 4));

    auto produce = [&](int kc, unsigned char* dst) {
        const float4 bv0 = *(const float4*)&sbm[kc + hj];
        const float4 bv1 = *(const float4*)&sbm[kc + hj + 4];
        const float4 u0  = *(const float4*)&swu[kc + hj];
        const float4 u1  = *(const float4*)&swu[kc + hj + 4];
        const float4 v0  = *(const float4*)&swv[kc + hj];
        const float4 v1  = *(const float4*)&swv[kc + hj + 4];
        f16x8 hv;
        hv[0] = (_Float16)fmaxf(fmaf(vm, v0.x, fmaf(um, u0.x, bv0.x)), 0.0f);
        hv[1] = (_Float16)fmaxf(fmaf(vm, v0.y, fmaf(um, u0.y, bv0.y)), 0.0f);
        hv[2] = (_Float16)fmaxf(fmaf(vm, v0.z, fmaf(um, u0.z, bv0.z)), 0.0f);
        hv[3] = (_Float16)fmaxf(fmaf(vm, v0.w, fmaf(um, u0.w, bv0.w)), 0.0f);
        hv[4] = (_Float16)fmaxf(fmaf(vm, v1.x, fmaf(um, u1.x, bv1.x)), 0.0f);
        hv[5] = (_Float16)fmaxf(fmaf(vm, v1.y, fmaf(um, u1.y, bv1.y)), 0.0f);
        hv[6] = (_Float16)fmaxf(fmaf(vm, v1.z, fmaf(um, u1.z, bv1.z)), 0.0f);
        hv[7] = (_Float16)fmaxf(fmaf(vm, v1.w, fmaf(um, u1.w, bv1.w)), 0.0f);
        *(f16x8*)(dst + hwoff) = hv;
    };

    // =======================  Layer 2: 64x512, K=1024  ======================
    f32x4 acc2[2][8];
    {
        const float* b2p = b2 + p * 512;
#pragma unroll
        for (int nf = 0; nf < 8; ++nf) {
            const float bias = b2p[wn * 128 + nf * 16 + l16];
            f32x4 bv = {bias, bias, bias, bias};
            acc2[0][nf] = bv;
            acc2[1][nf] = bv;
        }
    }
    const _Float16* Wt2p = Wt2 + (size_t)p * 512 * 1024;

    f16x8 bregA[2][8], bregB[2][8];

    // one pipelined chunk step: consumes bc (B regs, current), fills bn (next)
    auto l2step = [&](int ic, f16x8 (&bc)[2][8], f16x8 (&bn)[2][8]) {
        unsigned char* bufc = h1s[ic & 1];
        // A-frag reads for current chunk
        f16x8 a[2][2];
#pragma unroll
        for (int ks2 = 0; ks2 < 2; ++ks2) {
            const int kb = (ks2 * 32 + lq * 8) * 2;
            const int r0 = wm * 32 + l16;
            const int r1 = r0 + 16;
            a[ks2][0] = *(const f16x8*)(bufc + ((r0 * 128 + kb) ^ ((r0 & 7) << 4)));
            a[ks2][1] = *(const f16x8*)(bufc + ((r1 * 128 + kb) ^ ((r1 & 7) << 4)));
        }
        if (ic < 15) {
            const int kcn = (ic + 1) * 64;
            // issue next-chunk B loads (used NEXT iteration -> full-period cover)
#pragma unroll
            for (int ks2 = 0; ks2 < 2; ++ks2)
#pragma unroll
                for (int nf = 0; nf < 8; ++nf)
                    bn[ks2][nf] = *(const f16x8*)&Wt2p[(size_t)(wn * 128 + nf * 16 + l16) * 1024
                                                       + kcn + ks2 * 32 + lq * 8];
            // produce next h1 chunk into the other buffer (VALU cover)
            produce(kcn, h1s[(ic + 1) & 1]);
        }
        __builtin_amdgcn_s_setprio(1);
#pragma unroll
        for (int ks2 = 0; ks2 < 2; ++ks2)
#pragma unroll
            for (int nf = 0; nf < 8; ++nf) {
                acc2[0][nf] = __builtin_amdgcn_mfma_f32_16x16x32_f16(a[ks2][0], bc[ks2][nf], acc2[0][nf], 0, 0, 0);
                acc2[1][nf] = __builtin_amdgcn_mfma_f32_16x16x32_f16(a[ks2][1], bc[ks2][nf], acc2[1][nf], 0, 0, 0);
            }
        __builtin_amdgcn_s_setprio(0);
        __syncthreads();
    };

    // prologue: produce chunk 0, load chunk-0 B
    produce(0, h1s[0]);
#pragma unroll
    for (int ks2 = 0; ks2 < 2; ++ks2)
#pragma unroll
        for (int nf = 0; nf < 8; ++nf)
            bregA[ks2][nf] = *(const f16x8*)&Wt2p[(size_t)(wn * 128 + nf * 16 + l16) * 1024
                                                  + ks2 * 32 + lq * 8];
    __syncthreads();

#pragma unroll 1
    for (int ic = 0; ic < 16; ic += 2) {
        l2step(ic,     bregA, bregB);
        l2step(ic + 1, bregB, bregA);
    }

    // store h2 = relu(acc2) fp16, swizzled
#pragma unroll
    for (int msi = 0; msi < 2; ++msi)
#pragma unroll
        for (int nf = 0; nf < 8; ++nf)
#pragma unroll
            for (int r = 0; r < 4; ++r) {
                const int row = wm * 32 + msi * 16 + lq * 4 + r;
                const int col = wn * 128 + nf * 16 + l16;
                const float v = fmaxf(acc2[msi][nf][r], 0.0f);
                *(_Float16*)(h2s + ((row * 1024 + col * 2) ^ ((row & 7) << 4))) = (_Float16)v;
            }
    __syncthreads();

    // =======================  Layer 3: 64x256, K=512  =======================
    f32x4 acc3[2][4];
    {
        const float* b3p = b3 + p * 256;
#pragma unroll
        for (int nf = 0; nf < 4; ++nf) {
            const float bias = b3p[wn * 64 + nf * 16 + l16];
            f32x4 bv = {bias, bias, bias, bias};
            acc3[0][nf] = bv;
            acc3[1][nf] = bv;
        }
    }
    const _Float16* Wt3p = Wt3 + (size_t)p * 256 * 512;
#pragma unroll 4
    for (int ks = 0; ks < 512; ks += 32) {
        const int kb = (ks + lq * 8) * 2;
        const int r0 = wm * 32 + l16;
        const int r1 = r0 + 16;
        const f16x8 a0 = *(const f16x8*)(h2s + ((r0 * 1024 + kb) ^ ((r0 & 7) << 4)));
        const f16x8 a1 = *(const f16x8*)(h2s + ((r1 * 1024 + kb) ^ ((r1 & 7) << 4)));
#pragma unroll
        for (int nf = 0; nf < 4; ++nf) {
            const int n = wn * 64 + nf * 16 + l16;
            const f16x8 bf = *(const f16x8*)&Wt3p[(size_t)n * 512 + ks + lq * 8];
            acc3[0][nf] = __builtin_amdgcn_mfma_f32_16x16x32_f16(a0, bf, acc3[0][nf], 0, 0, 0);
            acc3[1][nf] = __builtin_amdgcn_mfma_f32_16x16x32_f16(a1, bf, acc3[1][nf], 0, 0, 0);
        }
    }
#pragma unroll
    for (int msi = 0; msi < 2; ++msi)
#pragma unroll
        for (int nf = 0; nf < 4; ++nf)
#pragma unroll
            for (int r = 0; r < 4; ++r) {
                const int row = wm * 32 + msi * 16 + lq * 4 + r;
                const int col = wn * 64 + nf * 16 + l16;
                const float v = fmaxf(acc3[msi][nf][r], 0.0f);
                *(_Float16*)(h3s + ((row * 512 + col * 2) ^ ((row & 7) << 4))) = (_Float16)v;
            }
    __syncthreads();

    // =======================  Layer 4: 64x128, K=256  =======================
    f32x4 acc4[2][2];
    {
        const float* b4p = b4 + p * 128;
#pragma unroll
        for (int nf = 0; nf < 2; ++nf) {
            const float bias = b4p[wn * 32 + nf * 16 + l16];
            f32x4 bv = {bias, bias, bias, bias};
            acc4[0][nf] = bv;
            acc4[1][nf] = bv;
        }
    }
    const _Float16* Wt4p = Wt4 + (size_t)p * 128 * 256;
#pragma unroll 4
    for (int ks = 0; ks < 256; ks += 32) {
        const int kb = (ks + lq * 8) * 2;
        const int r0 = wm * 32 + l16;
        const int r1 = r0 + 16;
        const f16x8 a0 = *(const f16x8*)(h3s + ((r0 * 512 + kb) ^ ((r0 & 7) << 4)));
        const f16x8 a1 = *(const f16x8*)(h3s + ((r1 * 512 + kb) ^ ((r1 & 7) << 4)));
#pragma unroll
        for (int nf = 0; nf < 2; ++nf) {
            const int n = wn * 32 + nf * 16 + l16;
            const f16x8 bf = *(const f16x8*)&Wt4p[(size_t)n * 256 + ks + lq * 8];
            acc4[0][nf] = __builtin_amdgcn_mfma_f32_16x16x32_f16(a0, bf, acc4[0][nf], 0, 0, 0);
            acc4[1][nf] = __builtin_amdgcn_mfma_f32_16x16x32_f16(a1, bf, acc4[1][nf], 0, 0, 0);
        }
    }
#pragma unroll
    for (int msi = 0; msi < 2; ++msi)
#pragma unroll
        for (int nf = 0; nf < 2; ++nf)
#pragma unroll
            for (int r = 0; r < 4; ++r) {
                const int row = wm * 32 + msi * 16 + lq * 4 + r;
                const int col = wn * 32 + nf * 16 + l16;
                const float v = fmaxf(acc4[msi][nf][r], 0.0f);
                *(_Float16*)(h4s + ((row * 256 + col * 2) ^ ((row & 7) << 4))) = (_Float16)v;
            }
    __syncthreads();

    // =======================  Layer 5: 64x3, K=128, tanh  ===================
    if (t < 192) {
        const int m = t / 3;
        const int c = t % 3;
        const float* W5p = W5 + p * 128 * 3;
        float acc = b5[p * 3 + c];
#pragma unroll 4
        for (int k = 0; k < 128; ++k) {
            const _Float16 hv = *(const _Float16*)(h4s + ((m * 256 + k * 2) ^ ((m & 7) << 4)));
            acc = fmaf((float)hv, W5p[k * 3 + c], acc);
        }
        const int r  = rbase + m;
        const int bb = r / 400;
        const int gg = r % 400;
        out[((size_t)(bb * K_PATCHES + p) * G_PTS + gg) * 3 + c] = tanhf(acc);
    }
}

extern "C" void kernel_launch(void* const* d_in, const int* in_sizes, int n_in,
                              void* d_out, int out_size, void* d_ws, size_t ws_size,
                              hipStream_t stream) {
    const float* x  = (const float*)d_in[0];
    const float* W1 = (const float*)d_in[1];
    const float* b1 = (const float*)d_in[2];
    const float* W2 = (const float*)d_in[3];
    const float* b2 = (const float*)d_in[4];
    const float* W3 = (const float*)d_in[5];
    const float* b3 = (const float*)d_in[6];
    const float* W4 = (const float*)d_in[7];
    const float* b4 = (const float*)d_in[8];
    const float* W5 = (const float*)d_in[9];
    const float* b5 = (const float*)d_in[10];
    float* out = (float*)d_out;

    float*     base = (float*)((char*)d_ws + BASE_OFF);
    _Float16*  Wt2  = (_Float16*)((char*)d_ws + WT2_OFF);
    _Float16*  Wt3  = (_Float16*)((char*)d_ws + WT3_OFF);
    _Float16*  Wt4  = (_Float16*)((char*)d_ws + WT4_OFF);

    base_kernel<<<K_PATCHES * 8, 128, 0, stream>>>(x, W1, b1, base);

    conv_tr_kernel<<<K_PATCHES * (1024 / 64) * (512 / 64), 256, 0, stream>>>(W2, Wt2, 1024, 512);
    conv_tr_kernel<<<K_PATCHES * (512 / 64) * (256 / 64),  256, 0, stream>>>(W3, Wt3, 512, 256);
    conv_tr_kernel<<<K_PATCHES * (256 / 64) * (128 / 64),  256, 0, stream>>>(W4, Wt4, 256, 128);

    fused_mfma<<<K_PATCHES * 100, 512, 0, stream>>>(
        base, W1, Wt2, b2, Wt3, b3, Wt4, b4, W5, b5, out);
}

// Round 4
// 517.109 us; speedup vs baseline: 8.5292x; 1.8495x over previous
//
#include <hip/hip_runtime.h>
#include <math.h>

#define K_PATCHES 25
#define GRID_SIDE 20
#define G_PTS     400
#define LATENT    1024
#define BATCH     16

typedef _Float16 f16x8 __attribute__((ext_vector_type(8)));
typedef _Float16 f16x4 __attribute__((ext_vector_type(4)));
typedef float    f32x4 __attribute__((ext_vector_type(4)));

// ws layout (bytes)
#define BASE_OFF 0                      // 16*25*1024 f32 = 1,638,400
#define WT2_OFF  1638400                // 25*512*1024 f16 = 26,214,400
#define WT3_OFF  27852800               // 25*256*512 f16  =  6,553,600
#define WT4_OFF  34406400               // 25*128*256 f16  =  1,638,400

// ---------------------------------------------------------------------------
// Kernel 1: base[b][p][o] = b1[p][o] + sum_k x[b][k]*W1[p][k][o]  (o<1024)
// ---------------------------------------------------------------------------
__global__ __launch_bounds__(128)
void base_kernel(const float* __restrict__ x,
                 const float* __restrict__ W1,
                 const float* __restrict__ b1,
                 float* __restrict__ base) {
    __shared__ float xs[BATCH][LATENT];   // 64 KB
    const int p  = blockIdx.x >> 3;
    const int oc = blockIdx.x & 7;
    const int o  = oc * 128 + threadIdx.x;

    for (int idx = threadIdx.x; idx < BATCH * LATENT / 4; idx += 128)
        ((float4*)xs)[idx] = ((const float4*)x)[idx];
    __syncthreads();

    float acc[BATCH];
#pragma unroll
    for (int b = 0; b < BATCH; ++b) acc[b] = 0.0f;

    const float* Wp = W1 + (size_t)p * 1026 * 1024 + o;
    for (int k = 0; k < LATENT; k += 4) {
        const float w0 = Wp[(size_t)(k + 0) * 1024];
        const float w1 = Wp[(size_t)(k + 1) * 1024];
        const float w2 = Wp[(size_t)(k + 2) * 1024];
        const float w3 = Wp[(size_t)(k + 3) * 1024];
#pragma unroll
        for (int b = 0; b < BATCH; ++b) {
            const float4 xv = *(const float4*)&xs[b][k];
            acc[b] = fmaf(xv.w, w3, fmaf(xv.z, w2, fmaf(xv.y, w1, fmaf(xv.x, w0, acc[b]))));
        }
    }

    const float bias = b1[p * 1024 + o];
    for (int b = 0; b < BATCH; ++b)
        base[(size_t)(b * K_PATCHES + p) * 1024 + o] = acc[b] + bias;
}

// ---------------------------------------------------------------------------
// Transpose + fp16 convert: W[p][K][N] f32 -> Wt[p][N][K] f16.
// ---------------------------------------------------------------------------
__global__ __launch_bounds__(256)
void conv_tr_kernel(const float* __restrict__ W, _Float16* __restrict__ Wt,
                    int K, int N) {
    __shared__ float tile[64][65];
    const int tpp = (K / 64) * (N / 64);
    const int p   = blockIdx.x / tpp;
    const int rem = blockIdx.x % tpp;
    const int kt  = rem / (N / 64);
    const int nt  = rem % (N / 64);
    const int tr  = threadIdx.x >> 6;
    const int tc  = threadIdx.x & 63;

    const float* Wp = W + ((size_t)p * K + kt * 64) * N + nt * 64;
#pragma unroll
    for (int i = 0; i < 64; i += 4)
        tile[i + tr][tc] = Wp[(size_t)(i + tr) * N + tc];
    __syncthreads();

    _Float16* Wtp = Wt + ((size_t)p * N + nt * 64) * K + kt * 64;
#pragma unroll
    for (int i = 0; i < 64; i += 4)
        Wtp[(size_t)(i + tr) * K + tc] = (_Float16)tile[tc][i + tr];
}

// ---------------------------------------------------------------------------
// Fused MFMA kernel, m201-style: B staged in LDS (shared by all 8 waves,
// read once from L2 per block), reg-staged with swizzle, double-buffered,
// one barrier per 32-K chunk, issue-early/write-late (T14), setprio (T5).
// Wave geometry: 8 waves, each owns full 64 M x (N/8) slice.
// LDS: one 152KB arena, per-layer aliasing.
// ---------------------------------------------------------------------------
__global__ __launch_bounds__(512)
void fused_mfma(const float* __restrict__ base,
                const float* __restrict__ W1,
                const _Float16* __restrict__ Wt2, const float* __restrict__ b2,
                const _Float16* __restrict__ Wt3, const float* __restrict__ b3,
                const _Float16* __restrict__ Wt4, const float* __restrict__ b4,
                const float* __restrict__ W5, const float* __restrict__ b5,
                float* __restrict__ out) {
    __shared__ __align__(16) unsigned char LDS[155648];
    constexpr int OFF_SB = 0;        // 8KB  sb[2][1024] f32   (layer2)
    constexpr int OFF_WU = 8192;     // 4KB                    (layer2)
    constexpr int OFF_WV = 12288;    // 4KB                    (layer2)
    constexpr int OFF_H1 = 16384;    // 2 x 4KB  h1 dbuf [64][32]f16
    constexpr int OFF_B2 = 24576;    // 2 x 32KB B2 dbuf [512][32]f16
    constexpr int OFF_H2 = 90112;    // 64KB  h2 [64][512]f16
    constexpr int OFF_B3 = 0;        // 2 x 16KB B3 dbuf [256][32]f16 (alias)
    constexpr int OFF_H3 = 32768;    // 32KB  h3 [64][256]f16 (alias)
    constexpr int OFF_B4 = 65536;    // 2 x 8KB B4 dbuf [128][32]f16 (alias)
    constexpr int OFF_H4 = 81920;    // 16KB  h4 [64][128]f16 (alias)

    // bijective XCD swizzle: 2500 blocks -> 8 XCDs, same-patch adjacency
    const int bid = blockIdx.x;
    const int xcd = bid & 7;
    const int ii  = bid >> 3;
    const int ord = (xcd < 4) ? xcd * 313 + ii : 4 * 313 + (xcd - 4) * 312 + ii;
    const int p     = ord / 100;
    const int rbase = (ord % 100) * 64;

    const int t    = threadIdx.x;
    const int lane = t & 63;
    const int w    = t >> 6;      // 0..7
    const int l16  = lane & 15;
    const int lq   = lane >> 4;   // 0..3

    float* sb0  = (float*)(LDS + OFF_SB);
    float* sb1  = sb0 + 1024;
    float* swuf = (float*)(LDS + OFF_WU);
    float* swvf = (float*)(LDS + OFF_WV);

    const int b0  = rbase / 400;
    const int b1i = (rbase + 63) / 400;
    {
        const float* base0 = base + (size_t)(b0 * K_PATCHES + p) * 1024;
        const float* base1 = base + (size_t)(b1i * K_PATCHES + p) * 1024;
        const float* wup   = W1 + (size_t)p * 1026 * 1024 + (size_t)1024 * 1024;
        if (t < 256) ((float4*)sb0)[t] = ((const float4*)base0)[t];
        else         ((float4*)sb1)[t - 256] = ((const float4*)base1)[t - 256];
        if (t < 256) ((float4*)swuf)[t] = ((const float4*)wup)[t];
        else         ((float4*)swvf)[t - 256] = ((const float4*)(wup + 1024))[t - 256];
    }
    __syncthreads();

    // h1 producer constants: thread t owns row hm (0..63), 4-elem quad hq (0..7)
    const int hm = t >> 3;
    const int hq = t & 7;
    const int rr = rbase + hm;
    const float* sbm = (rr < (b0 + 1) * 400) ? sb0 : sb1;
    const int g  = rr % 400;
    const float um = (float)(g % GRID_SIDE) * (1.0f / 19.0f);
    const float vm = (float)(g / GRID_SIDE) * (1.0f / 19.0f);
    const unsigned hwoff = (unsigned)(hm * 64 + (((hq >> 1) ^ (hm & 3)) << 4) + ((hq & 1) << 3));

    auto produce = [&](int kc, unsigned char* dst) {
        const float4 bv = *(const float4*)&sbm[kc + hq * 4];
        const float4 uu = *(const float4*)&swuf[kc + hq * 4];
        const float4 vv = *(const float4*)&swvf[kc + hq * 4];
        f16x4 hv;
        hv[0] = (_Float16)fmaxf(fmaf(vm, vv.x, fmaf(um, uu.x, bv.x)), 0.0f);
        hv[1] = (_Float16)fmaxf(fmaf(vm, vv.y, fmaf(um, uu.y, bv.y)), 0.0f);
        hv[2] = (_Float16)fmaxf(fmaf(vm, vv.z, fmaf(um, uu.z, bv.z)), 0.0f);
        hv[3] = (_Float16)fmaxf(fmaf(vm, vv.w, fmaf(um, uu.w, bv.w)), 0.0f);
        *(f16x4*)(dst + hwoff) = hv;
    };

    // =======================  Layer 2: 64x512, K=1024  ======================
    const _Float16* Wt2p = Wt2 + (size_t)p * 512 * 1024;
    f32x4 acc2[4][4];
    {
        const float* b2p = b2 + p * 512;
#pragma unroll
        for (int nf = 0; nf < 4; ++nf) {
            const float bias = b2p[w * 64 + nf * 16 + l16];
            f32x4 bv = {bias, bias, bias, bias};
#pragma unroll
            for (int mf = 0; mf < 4; ++mf) acc2[mf][nf] = bv;
        }
    }

    produce(0, LDS + OFF_H1);
    {
        f16x8 st[4];
#pragma unroll
        for (int j = 0; j < 4; ++j) {
            const int n = (t >> 2) + 128 * j;
            st[j] = *(const f16x8*)&Wt2p[(size_t)n * 1024 + (t & 3) * 8];
        }
        unsigned char* nb = LDS + OFF_B2;
#pragma unroll
        for (int j = 0; j < 4; ++j) {
            const int n = (t >> 2) + 128 * j;
            *(f16x8*)(nb + n * 64 + (((t & 3) ^ (n & 3)) << 4)) = st[j];
        }
    }
    __syncthreads();

#pragma unroll 1
    for (int c = 0; c < 32; ++c) {
        unsigned char* h1b = LDS + OFF_H1 + (c & 1) * 4096;
        unsigned char* b2b = LDS + OFF_B2 + (c & 1) * 32768;
        f16x8 st[4];
        const int kc1 = (c + 1) * 32;
        if (c < 31) {
#pragma unroll
            for (int j = 0; j < 4; ++j) {
                const int n = (t >> 2) + 128 * j;
                st[j] = *(const f16x8*)&Wt2p[(size_t)n * 1024 + kc1 + (t & 3) * 8];
            }
            produce(kc1, LDS + OFF_H1 + ((c + 1) & 1) * 4096);
        }
        f16x8 a[4], bfr[4];
#pragma unroll
        for (int mf = 0; mf < 4; ++mf) {
            const int r = mf * 16 + l16;
            a[mf] = *(const f16x8*)(h1b + r * 64 + ((lq ^ (r & 3)) << 4));
        }
#pragma unroll
        for (int nf = 0; nf < 4; ++nf) {
            const int n = w * 64 + nf * 16 + l16;
            bfr[nf] = *(const f16x8*)(b2b + n * 64 + ((lq ^ (n & 3)) << 4));
        }
        __builtin_amdgcn_s_setprio(1);
#pragma unroll
        for (int mf = 0; mf < 4; ++mf)
#pragma unroll
            for (int nf = 0; nf < 4; ++nf)
                acc2[mf][nf] = __builtin_amdgcn_mfma_f32_16x16x32_f16(a[mf], bfr[nf], acc2[mf][nf], 0, 0, 0);
        __builtin_amdgcn_s_setprio(0);
        if (c < 31) {
            unsigned char* nb = LDS + OFF_B2 + ((c + 1) & 1) * 32768;
#pragma unroll
            for (int j = 0; j < 4; ++j) {
                const int n = (t >> 2) + 128 * j;
                *(f16x8*)(nb + n * 64 + (((t & 3) ^ (n & 3)) << 4)) = st[j];
            }
        }
        __syncthreads();
    }

#pragma unroll
    for (int mf = 0; mf < 4; ++mf)
#pragma unroll
        for (int nf = 0; nf < 4; ++nf)
#pragma unroll
            for (int r = 0; r < 4; ++r) {
                const int row = mf * 16 + lq * 4 + r;
                const int col = w * 64 + nf * 16 + l16;
                const float v = fmaxf(acc2[mf][nf][r], 0.0f);
                *(_Float16*)(LDS + OFF_H2 + ((row * 1024 + col * 2) ^ ((row & 7) << 4))) = (_Float16)v;
            }

    // =======================  Layer 3: 64x256, K=512  =======================
    const _Float16* Wt3p = Wt3 + (size_t)p * 256 * 512;
    f32x4 acc3[4][2];
    {
        const float* b3p = b3 + p * 256;
#pragma unroll
        for (int nf = 0; nf < 2; ++nf) {
            const float bias = b3p[w * 32 + nf * 16 + l16];
            f32x4 bv = {bias, bias, bias, bias};
#pragma unroll
            for (int mf = 0; mf < 4; ++mf) acc3[mf][nf] = bv;
        }
    }
    {
        f16x8 st[2];
#pragma unroll
        for (int j = 0; j < 2; ++j) {
            const int n = (t >> 2) + 128 * j;
            st[j] = *(const f16x8*)&Wt3p[(size_t)n * 512 + (t & 3) * 8];
        }
        unsigned char* nb = LDS + OFF_B3;
#pragma unroll
        for (int j = 0; j < 2; ++j) {
            const int n = (t >> 2) + 128 * j;
            *(f16x8*)(nb + n * 64 + (((t & 3) ^ (n & 3)) << 4)) = st[j];
        }
    }
    __syncthreads();

#pragma unroll 1
    for (int c = 0; c < 16; ++c) {
        unsigned char* b3b = LDS + OFF_B3 + (c & 1) * 16384;
        const int kc = c * 32;
        f16x8 st[2];
        if (c < 15) {
            const int kc1 = kc + 32;
#pragma unroll
            for (int j = 0; j < 2; ++j) {
                const int n = (t >> 2) + 128 * j;
                st[j] = *(const f16x8*)&Wt3p[(size_t)n * 512 + kc1 + (t & 3) * 8];
            }
        }
        f16x8 a[4], bfr[2];
#pragma unroll
        for (int mf = 0; mf < 4; ++mf) {
            const int r = mf * 16 + l16;
            a[mf] = *(const f16x8*)(LDS + OFF_H2 + ((r * 1024 + (kc + lq * 8) * 2) ^ ((r & 7) << 4)));
        }
#pragma unroll
        for (int nf = 0; nf < 2; ++nf) {
            const int n = w * 32 + nf * 16 + l16;
            bfr[nf] = *(const f16x8*)(b3b + n * 64 + ((lq ^ (n & 3)) << 4));
        }
        __builtin_amdgcn_s_setprio(1);
#pragma unroll
        for (int mf = 0; mf < 4; ++mf)
#pragma unroll
            for (int nf = 0; nf < 2; ++nf)
                acc3[mf][nf] = __builtin_amdgcn_mfma_f32_16x16x32_f16(a[mf], bfr[nf], acc3[mf][nf], 0, 0, 0);
        __builtin_amdgcn_s_setprio(0);
        if (c < 15) {
            unsigned char* nb = LDS + OFF_B3 + ((c + 1) & 1) * 16384;
#pragma unroll
            for (int j = 0; j < 2; ++j) {
                const int n = (t >> 2) + 128 * j;
                *(f16x8*)(nb + n * 64 + (((t & 3) ^ (n & 3)) << 4)) = st[j];
            }
        }
        __syncthreads();
    }

#pragma unroll
    for (int mf = 0; mf < 4; ++mf)
#pragma unroll
        for (int nf = 0; nf < 2; ++nf)
#pragma unroll
            for (int r = 0; r < 4; ++r) {
                const int row = mf * 16 + lq * 4 + r;
                const int col = w * 32 + nf * 16 + l16;
                const float v = fmaxf(acc3[mf][nf][r], 0.0f);
                *(_Float16*)(LDS + OFF_H3 + ((row * 512 + col * 2) ^ ((row & 7) << 4))) = (_Float16)v;
            }

    // =======================  Layer 4: 64x128, K=256  =======================
    const _Float16* Wt4p = Wt4 + (size_t)p * 128 * 256;
    f32x4 acc4[4];
    {
        const float* b4p = b4 + p * 128;
        const float bias = b4p[w * 16 + l16];
        f32x4 bv = {bias, bias, bias, bias};
#pragma unroll
        for (int mf = 0; mf < 4; ++mf) acc4[mf] = bv;
    }
    {
        const int n = t >> 2;
        f16x8 st0 = *(const f16x8*)&Wt4p[(size_t)n * 256 + (t & 3) * 8];
        *(f16x8*)(LDS + OFF_B4 + n * 64 + (((t & 3) ^ (n & 3)) << 4)) = st0;
    }
    __syncthreads();

#pragma unroll 1
    for (int c = 0; c < 8; ++c) {
        unsigned char* b4b = LDS + OFF_B4 + (c & 1) * 8192;
        const int kc = c * 32;
        f16x8 st0;
        if (c < 7) {
            const int n = t >> 2;
            st0 = *(const f16x8*)&Wt4p[(size_t)n * 256 + kc + 32 + (t & 3) * 8];
        }
        f16x8 a[4], bfr;
#pragma unroll
        for (int mf = 0; mf < 4; ++mf) {
            const int r = mf * 16 + l16;
            a[mf] = *(const f16x8*)(LDS + OFF_H3 + ((r * 512 + (kc + lq * 8) * 2) ^ ((r & 7) << 4)));
        }
        {
            const int n = w * 16 + l16;
            bfr = *(const f16x8*)(b4b + n * 64 + ((lq ^ (n & 3)) << 4));
        }
        __builtin_amdgcn_s_setprio(1);
#pragma unroll
        for (int mf = 0; mf < 4; ++mf)
            acc4[mf] = __builtin_amdgcn_mfma_f32_16x16x32_f16(a[mf], bfr, acc4[mf], 0, 0, 0);
        __builtin_amdgcn_s_setprio(0);
        if (c < 7) {
            unsigned char* nb = LDS + OFF_B4 + ((c + 1) & 1) * 8192;
            const int n = t >> 2;
            *(f16x8*)(nb + n * 64 + (((t & 3) ^ (n & 3)) << 4)) = st0;
        }
        __syncthreads();
    }

#pragma unroll
    for (int mf = 0; mf < 4; ++mf)
#pragma unroll
        for (int r = 0; r < 4; ++r) {
            const int row = mf * 16 + lq * 4 + r;
            const int col = w * 16 + l16;
            const float v = fmaxf(acc4[mf][r], 0.0f);
            *(_Float16*)(LDS + OFF_H4 + ((row * 256 + col * 2) ^ ((row & 7) << 4))) = (_Float16)v;
        }
    __syncthreads();

    // =======================  Layer 5: 64x3, K=128, tanh  ===================
    if (t < 192) {
        const int m = t / 3;
        const int c = t % 3;
        const float* W5p = W5 + p * 128 * 3;
        float acc = b5[p * 3 + c];
#pragma unroll 4
        for (int k = 0; k < 128; ++k) {
            const _Float16 hv = *(const _Float16*)(LDS + OFF_H4 + ((m * 256 + k * 2) ^ ((m & 7) << 4)));
            acc = fmaf((float)hv, W5p[k * 3 + c], acc);
        }
        const int r  = rbase + m;
        const int bb = r / 400;
        const int gg = r % 400;
        out[((size_t)(bb * K_PATCHES + p) * G_PTS + gg) * 3 + c] = tanhf(acc);
    }
}

extern "C" void kernel_launch(void* const* d_in, const int* in_sizes, int n_in,
                              void* d_out, int out_size, void* d_ws, size_t ws_size,
                              hipStream_t stream) {
    const float* x  = (const float*)d_in[0];
    const float* W1 = (const float*)d_in[1];
    const float* b1 = (const float*)d_in[2];
    const float* W2 = (const float*)d_in[3];
    const float* b2 = (const float*)d_in[4];
    const float* W3 = (const float*)d_in[5];
    const float* b3 = (const float*)d_in[6];
    const float* W4 = (const float*)d_in[7];
    const float* b4 = (const float*)d_in[8];
    const float* W5 = (const float*)d_in[9];
    const float* b5 = (const float*)d_in[10];
    float* out = (float*)d_out;

    float*     base = (float*)((char*)d_ws + BASE_OFF);
    _Float16*  Wt2  = (_Float16*)((char*)d_ws + WT2_OFF);
    _Float16*  Wt3  = (_Float16*)((char*)d_ws + WT3_OFF);
    _Float16*  Wt4  = (_Float16*)((char*)d_ws + WT4_OFF);

    base_kernel<<<K_PATCHES * 8, 128, 0, stream>>>(x, W1, b1, base);

    conv_tr_kernel<<<K_PATCHES * (1024 / 64) * (512 / 64), 256, 0, stream>>>(W2, Wt2, 1024, 512);
    conv_tr_kernel<<<K_PATCHES * (512 / 64) * (256 / 64),  256, 0, stream>>>(W3, Wt3, 512, 256);
    conv_tr_kernel<<<K_PATCHES * (256 / 64) * (128 / 64),  256, 0, stream>>>(W4, Wt4, 256, 128);

    fused_mfma<<<K_PATCHES * 100, 512, 0, stream>>>(
        base, W1, Wt2, b2, Wt3, b3, Wt4, b4, W5, b5, out);
}